// Round 12
// baseline (144.783 us; speedup 1.0000x reference)
//
#include <hip/hip_runtime.h>

#define N_NODES 50000
#define N_EDGES 800000
#define FEATS   128
#define N_CLASSES 47
#define NPAD    50176        // 196 * 256
#define NBUK    196          // buckets of 256 nodes (dst >> 8)
#define EB      2048         // edges per bucket_scatter block
#define CAP     6144         // padded bucket capacity (avg 4096, sigma 64 -> +32 sigma)
#define CVT8    ((N_NODES * FEATS / 8 + 255) / 256)   // 3125 blocks for x->bf16

typedef __attribute__((ext_vector_type(8))) short short8v;   // 8 bf16 = 4 VGPRs
typedef __attribute__((ext_vector_type(4))) float float4v;   // 4 f32 acc

// ------------------------------------------------------------ bf16 helpers --
static __device__ __forceinline__ unsigned short f2bf(float f) {
    union { float f; unsigned u; } v; v.f = f;
    return (unsigned short)((v.u + 0x7fffu + ((v.u >> 16) & 1u)) >> 16);  // RNE
}
static __device__ __forceinline__ unsigned pack2(float a, float b) {
    return (unsigned)f2bf(a) | ((unsigned)f2bf(b) << 16);
}
static __device__ __forceinline__ void acc2(unsigned u, float& a, float& b) {
    union { unsigned u; float f; } lo, hi;
    lo.u = u << 16; hi.u = u & 0xffff0000u;
    a += lo.f; b += hi.f;
}

// ===================== prep: x->bf16, W->bf16^T, gcursor=0 (one kernel) =====
__global__ __launch_bounds__(256) void prep_all(const float* __restrict__ x,
                                                unsigned short* __restrict__ xb,
                                                const float* __restrict__ Ws0,
                                                const float* __restrict__ Wn0,
                                                const float* __restrict__ Ws1,
                                                const float* __restrict__ Wn1,
                                                const float* __restrict__ Ws2,
                                                const float* __restrict__ Wn2,
                                                unsigned short* __restrict__ Wt0,
                                                unsigned short* __restrict__ Wt1,
                                                unsigned short* __restrict__ Wt2,
                                                int* __restrict__ gcursor) {
    const int b = blockIdx.x;
    if (b < CVT8) {
        const int t = b * 256 + threadIdx.x;
        if (t < N_NODES * FEATS / 8) {
            const float4* p = reinterpret_cast<const float4*>(x + (size_t)t * 8);
            float4 a = p[0], c = p[1];
            uint4 o;
            o.x = pack2(a.x, a.y); o.y = pack2(a.z, a.w);
            o.z = pack2(c.x, c.y); o.w = pack2(c.z, c.w);
            *reinterpret_cast<uint4*>(xb + (size_t)t * 8) = o;
        }
    } else if (b < CVT8 + 256) {
        // Wt0 / Wt1: [j][k], k<128 -> Ws[k][j], else Wn[k-128][j]
        const int t = (b - CVT8) * 256 + threadIdx.x;    // < 256*256
        const int j = t >> 8, k = t & 255;
        const float* Ws; const float* Wn; unsigned short* Wt; size_t idx; int jj;
        if (j < 128) { Ws = Ws0; Wn = Wn0; Wt = Wt0; idx = (size_t)j * 256 + k; jj = j; }
        else         { Ws = Ws1; Wn = Wn1; Wt = Wt1; idx = (size_t)(j - 128) * 256 + k; jj = j - 128; }
        const float v = (k < 128) ? Ws[(size_t)k * 128 + jj] : Wn[(size_t)(k - 128) * 128 + jj];
        Wt[idx] = f2bf(v);
    } else if (b < CVT8 + 320) {
        // Wt2: [j2][k], j2<64 -> Ws2 col j2 (47 used), j2>=64 -> Wn2 col j2-64; K=128
        const int wb2 = b - CVT8 - 256;                  // 0..63
        const int j2 = wb2 * 2 + (threadIdx.x >> 7);     // 0..127
        const int k  = threadIdx.x & 127;
        float v = 0.0f;
        if (j2 < 64) { if (j2 < N_CLASSES) v = Ws2[(size_t)k * N_CLASSES + j2]; }
        else { const int jn = j2 - 64; if (jn < N_CLASSES) v = Wn2[(size_t)k * N_CLASSES + jn]; }
        Wt2[(size_t)j2 * 128 + k] = f2bf(v);
    } else {
        gcursor[threadIdx.x] = 0;
    }
}

// ============================ CSR build (bucket counting sort) ==============
__global__ __launch_bounds__(256) void bucket_scatter(const int* __restrict__ src,
                                                      const int* __restrict__ dst,
                                                      int* __restrict__ gcursor,
                                                      unsigned* __restrict__ ebuf, int E) {
    __shared__ int hist[NBUK], lscan[NBUK], lcur[NBUK], sbase[NBUK];
    __shared__ int s[256];
    __shared__ unsigned stage[EB];                    // 8 KB
    const int t = threadIdx.x;
    const int e0 = blockIdx.x * EB;
    const int tot = min(EB, E - e0);

    unsigned pk[8]; int bk[8];
#pragma unroll
    for (int k = 0; k < 8; ++k) {
        const int i = k * 256 + t;
        if (i < tot) {
            const int d = dst[e0 + i];
            pk[k] = ((unsigned)src[e0 + i] << 16) | (unsigned)d;
            bk[k] = d >> 8;
        } else { pk[k] = 0; bk[k] = -1; }
    }

    if (t < NBUK) { hist[t] = 0; lcur[t] = 0; }
    __syncthreads();
#pragma unroll
    for (int k = 0; k < 8; ++k)
        if (bk[k] >= 0) atomicAdd(&hist[bk[k]], 1);
    __syncthreads();

    const int v = (t < NBUK) ? hist[t] : 0;
    s[t] = v;
    __syncthreads();
    for (int off = 1; off < 256; off <<= 1) {
        int x = (t >= off) ? s[t - off] : 0;
        __syncthreads();
        s[t] += x;
        __syncthreads();
    }
    if (t < NBUK) {
        lscan[t] = s[t] - v;
        sbase[t] = v ? atomicAdd(&gcursor[t], v) : 0;
    }
    __syncthreads();

#pragma unroll
    for (int k = 0; k < 8; ++k) {
        if (bk[k] >= 0) {
            const int p = lscan[bk[k]] + atomicAdd(&lcur[bk[k]], 1);
            stage[p] = pk[k];
        }
    }
    __syncthreads();

    for (int i = t; i < tot; i += 256) {
        const unsigned p = stage[i];
        const int b = (int)((p & 0xffffu) >> 8);
        const int off = sbase[b] + (i - lscan[b]);
        if (off < CAP) ebuf[(size_t)b * CAP + off] = p;   // guard: statistically dead
    }
}

__global__ __launch_bounds__(256) void bucket_finalize(const unsigned* __restrict__ ebuf,
                                                       const int* __restrict__ gcursor,
                                                       int* __restrict__ row_beg,
                                                       int* __restrict__ row_end,
                                                       float* __restrict__ invdeg,
                                                       unsigned short* __restrict__ e_src) {
    __shared__ int hist[256], lscan[256], lcur[256], s[256];
    const int b = blockIdx.x, t = threadIdx.x;
    hist[t] = 0; lcur[t] = 0;
    __syncthreads();

    const int base = b * CAP;
    const int cnt  = min(gcursor[b], CAP);
    for (int i = t; i < cnt; i += 256)
        atomicAdd(&hist[ebuf[base + i] & 255], 1);
    __syncthreads();

    const int v = hist[t];
    s[t] = v;
    __syncthreads();
    for (int off = 1; off < 256; off <<= 1) {
        int x = (t >= off) ? s[t - off] : 0;
        __syncthreads();
        s[t] += x;
        __syncthreads();
    }
    lscan[t] = s[t] - v;
    __syncthreads();

    const int gnode = b * 256 + t;
    row_beg[gnode] = base + lscan[t];
    row_end[gnode] = base + lscan[t] + v;
    invdeg[gnode]  = 1.0f / fmaxf((float)v, 1.0f);

    for (int i = t; i < cnt; i += 256) {
        const unsigned p = ebuf[base + i];
        const int dl = p & 255;
        const int pos = base + lscan[dl] + atomicAdd(&lcur[dl], 1);
        e_src[pos] = (unsigned short)(p >> 16);
    }
}

// --------------------------------------------------------- CSR mean-gather --
// 16 lanes per node; lane handles feats [8*lane, 8*lane+8). bf16 in, f32 acc,
// bf16 out (pre-scaled by invdeg). 4-deep ILP; high occupancy (no LDS) —
// R9 lesson: this latency/L3-bound phase must NOT be fused behind big LDS.
__global__ __launch_bounds__(256) void gather_bf16_kernel(const unsigned short* __restrict__ hb,
                                                          const unsigned short* __restrict__ e_src,
                                                          const int* __restrict__ row_beg,
                                                          const int* __restrict__ row_end,
                                                          const float* __restrict__ invdeg,
                                                          unsigned short* __restrict__ hnb,
                                                          int n) {
    int t = blockIdx.x * blockDim.x + threadIdx.x;
    int node = t >> 4;
    int lane = t & 15;
    if (node >= n) return;
    int beg = row_beg[node];
    int end = row_end[node];

    float a0=0,a1=0,a2=0,a3=0,a4=0,a5=0,a6=0,a7=0;
    int i = beg;
    for (; i + 3 < end; i += 4) {
        int s0 = e_src[i], s1 = e_src[i+1], s2 = e_src[i+2], s3 = e_src[i+3];
        uint4 v0 = *reinterpret_cast<const uint4*>(hb + (size_t)s0 * FEATS + lane * 8);
        uint4 v1 = *reinterpret_cast<const uint4*>(hb + (size_t)s1 * FEATS + lane * 8);
        uint4 v2 = *reinterpret_cast<const uint4*>(hb + (size_t)s2 * FEATS + lane * 8);
        uint4 v3 = *reinterpret_cast<const uint4*>(hb + (size_t)s3 * FEATS + lane * 8);
        acc2(v0.x, a0, a1); acc2(v0.y, a2, a3); acc2(v0.z, a4, a5); acc2(v0.w, a6, a7);
        acc2(v1.x, a0, a1); acc2(v1.y, a2, a3); acc2(v1.z, a4, a5); acc2(v1.w, a6, a7);
        acc2(v2.x, a0, a1); acc2(v2.y, a2, a3); acc2(v2.z, a4, a5); acc2(v2.w, a6, a7);
        acc2(v3.x, a0, a1); acc2(v3.y, a2, a3); acc2(v3.z, a4, a5); acc2(v3.w, a6, a7);
    }
    for (; i < end; ++i) {
        int s0 = e_src[i];
        uint4 v0 = *reinterpret_cast<const uint4*>(hb + (size_t)s0 * FEATS + lane * 8);
        acc2(v0.x, a0, a1); acc2(v0.y, a2, a3); acc2(v0.z, a4, a5); acc2(v0.w, a6, a7);
    }
    const float g = invdeg[node];
    uint4 o;
    o.x = pack2(a0 * g, a1 * g); o.y = pack2(a2 * g, a3 * g);
    o.z = pack2(a4 * g, a5 * g); o.w = pack2(a6 * g, a7 * g);
    *reinterpret_cast<uint4*>(hnb + (size_t)node * FEATS + lane * 8) = o;
}

// ------------------------------------------------------- MFMA fused GEMM ----
// Layer 0: C[M,128] = [hb|hnb](bf16, K=256) @ Wt^T + bias, ReLU, bf16 out.
// R12: 256 nodes/block (4 m-tiles/wave) — halves redundant weight staging.
// Wt staged with XOR swizzle (ushort idx ^= (row&7)<<3) -> conflict-free
// ds_read_b128. C/D: col=lane&15, row=(lane>>4)*4+reg (m89-verified).
__global__ __launch_bounds__(256) void sage_gemm(const unsigned short* __restrict__ hb,
                                                 const unsigned short* __restrict__ hnb,
                                                 const unsigned short* __restrict__ Wt,
                                                 const float* __restrict__ bias,
                                                 unsigned short* __restrict__ outb, int n) {
    __shared__ unsigned short lds[128 * 256];        // 64KB
    const int t = threadIdx.x;
#pragma unroll
    for (int it = 0; it < 16; ++it) {
        int g = (it * 256 + t) * 8;
        int row = g >> 8;
        int swz = g ^ ((row & 7) << 3);
        *reinterpret_cast<uint4*>(&lds[swz]) = *reinterpret_cast<const uint4*>(Wt + g);
    }
    __syncthreads();

    const int lane = t & 63, wave = t >> 6;
    const int node0 = blockIdx.x * 256 + wave * 64;  // wave owns rows [node0, node0+64)
    const int r16 = lane & 15, q = lane >> 4;
    int arow[4];
#pragma unroll
    for (int m = 0; m < 4; ++m) {
        const int rn = node0 + m * 16 + r16;
        arow[m] = (rn < n) ? rn : 0;
    }

    float4v acc[4][8];
#pragma unroll
    for (int m = 0; m < 4; ++m)
#pragma unroll
        for (int nt = 0; nt < 8; ++nt) acc[m][nt] = float4v{0.f, 0.f, 0.f, 0.f};

#pragma unroll
    for (int ks = 0; ks < 8; ++ks) {                 // k = ks*32; first 4 from hb
        const unsigned short* abase = (ks < 4) ? hb : hnb;
        const int kk = (ks & 3) * 32 + q * 8;
        short8v af[4];
#pragma unroll
        for (int m = 0; m < 4; ++m)
            af[m] = *reinterpret_cast<const short8v*>(abase + (size_t)arow[m] * FEATS + kk);
#pragma unroll
        for (int nt = 0; nt < 8; ++nt) {
            const int brow = nt * 16 + r16;
            int bidx = ((brow << 8) + ks * 32 + q * 8) ^ ((brow & 7) << 3);
            short8v bf = *reinterpret_cast<const short8v*>(&lds[bidx]);
#pragma unroll
            for (int m = 0; m < 4; ++m)
                acc[m][nt] = __builtin_amdgcn_mfma_f32_16x16x32_bf16(af[m], bf, acc[m][nt], 0, 0, 0);
        }
    }

#pragma unroll
    for (int m = 0; m < 4; ++m) {
#pragma unroll
        for (int nt = 0; nt < 8; ++nt) {
            const int j = nt * 16 + r16;             // C col = lane&15
            const float bv = bias[j];
#pragma unroll
            for (int r = 0; r < 4; ++r) {
                const int rown = node0 + m * 16 + q * 4 + r;  // C row
                if (rown >= n) continue;
                outb[(size_t)rown * 128 + j] = f2bf(fmaxf(acc[m][nt][r] + bv, 0.0f));
            }
        }
    }
}

// ================= fused layers 1+2: GEMM1 -> LDS h2 tile -> dual GEMM2 =====
// Stage A (K=256): h2 = relu([h1|hn1] @ Wt1 + b1) for the block's 128 rows.
// h2 @ Wt2 is ROW-LOCAL, so stage B runs in the same block: after a barrier
// the Wt1 LDS is dead; overlay h2 tile (32KB, rows swizzled) + Wt2 (32KB).
// Stage B (K=128): sb2 = h2 @ Ws2 + b2 (bf16), z2 = h2 @ Wn2 (bf16).
// R12 RACE FIX: z2 is now a SEPARATE buffer (R11 aliased z2=hnb; with 64- vs
// 128-wide rows, block g's z2 writes clobbered block g/2's stage-A hnb input —
// passed only by timing luck since stage-A reads are early and writes late).
__global__ __launch_bounds__(256) void sage_gemm_l12(const unsigned short* __restrict__ hb,
                                                     const unsigned short* __restrict__ hnb,
                                                     const unsigned short* __restrict__ Wt1,
                                                     const float* __restrict__ b1,
                                                     const unsigned short* __restrict__ Wt2,
                                                     const float* __restrict__ b2,
                                                     unsigned short* __restrict__ sb2,
                                                     unsigned short* __restrict__ z2, int n) {
    __shared__ unsigned short lds[128 * 256];        // 64KB, overlaid per phase
    const int t = threadIdx.x;
#pragma unroll
    for (int it = 0; it < 16; ++it) {
        int g = (it * 256 + t) * 8;
        int row = g >> 8;
        int swz = g ^ ((row & 7) << 3);
        *reinterpret_cast<uint4*>(&lds[swz]) = *reinterpret_cast<const uint4*>(Wt1 + g);
    }
    __syncthreads();

    const int lane = t & 63, wave = t >> 6;
    const int node0 = blockIdx.x * 128 + wave * 32;
    const int lrow0 = wave * 32;                     // block-local row base of this wave
    const int r16 = lane & 15, q = lane >> 4;
    const int arown0 = node0 + r16;
    const int arown1 = node0 + 16 + r16;
    const int arow0 = (arown0 < n) ? arown0 : 0;
    const int arow1 = (arown1 < n) ? arown1 : 0;

    float4v acc[2][8];
#pragma unroll
    for (int m = 0; m < 2; ++m)
#pragma unroll
        for (int nt = 0; nt < 8; ++nt) acc[m][nt] = float4v{0.f, 0.f, 0.f, 0.f};

    // ---- stage A: K=256 over [hb|hnb] ----
#pragma unroll
    for (int ks = 0; ks < 8; ++ks) {
        const unsigned short* abase = (ks < 4) ? hb : hnb;
        const int kk = (ks & 3) * 32 + q * 8;
        short8v af0 = *reinterpret_cast<const short8v*>(abase + (size_t)arow0 * FEATS + kk);
        short8v af1 = *reinterpret_cast<const short8v*>(abase + (size_t)arow1 * FEATS + kk);
#pragma unroll
        for (int nt = 0; nt < 8; ++nt) {
            const int brow = nt * 16 + r16;
            int bidx = ((brow << 8) + ks * 32 + q * 8) ^ ((brow & 7) << 3);
            short8v bf = *reinterpret_cast<const short8v*>(&lds[bidx]);
            acc[0][nt] = __builtin_amdgcn_mfma_f32_16x16x32_bf16(af0, bf, acc[0][nt], 0, 0, 0);
            acc[1][nt] = __builtin_amdgcn_mfma_f32_16x16x32_bf16(af1, bf, acc[1][nt], 0, 0, 0);
        }
    }
    __syncthreads();                                 // all Wt1 reads done; LDS reusable

    // ---- overlay: h2 tile [128][128] bf16 at lds[0..16384) (row-swizzled) ----
    //                Wt2   [128][128] bf16 at lds[16384..32768)
#pragma unroll
    for (int m = 0; m < 2; ++m) {
#pragma unroll
        for (int nt = 0; nt < 8; ++nt) {
            const int col = nt * 16 + r16;
            const float bv = b1[col];
#pragma unroll
            for (int r = 0; r < 4; ++r) {
                const int lr = lrow0 + m * 16 + q * 4 + r;
                const int hidx = ((lr << 7) + col) ^ ((lr & 7) << 3);
                lds[hidx] = f2bf(fmaxf(acc[m][nt][r] + bv, 0.0f));
            }
        }
    }
#pragma unroll
    for (int it = 0; it < 8; ++it) {                 // stage Wt2 (32 KB)
        int g = (it * 256 + t) * 8;
        int row = g >> 7;
        int swz = g ^ ((row & 7) << 3);
        *reinterpret_cast<uint4*>(&lds[16384 + swz]) = *reinterpret_cast<const uint4*>(Wt2 + g);
    }
    __syncthreads();

    // ---- stage B: K=128 over h2 tile ----
#pragma unroll
    for (int m = 0; m < 2; ++m)
#pragma unroll
        for (int nt = 0; nt < 8; ++nt) acc[m][nt] = float4v{0.f, 0.f, 0.f, 0.f};

#pragma unroll
    for (int ks = 0; ks < 4; ++ks) {
        const int kk = ks * 32 + q * 8;
        const int ar0 = lrow0 + r16, ar1 = lrow0 + 16 + r16;
        const int aidx0 = ((ar0 << 7) + kk) ^ ((ar0 & 7) << 3);
        const int aidx1 = ((ar1 << 7) + kk) ^ ((ar1 & 7) << 3);
        short8v af0 = *reinterpret_cast<const short8v*>(&lds[aidx0]);
        short8v af1 = *reinterpret_cast<const short8v*>(&lds[aidx1]);
#pragma unroll
        for (int nt = 0; nt < 8; ++nt) {
            const int brow = nt * 16 + r16;
            int bidx = 16384 + (((brow << 7) + kk) ^ ((brow & 7) << 3));
            short8v bf = *reinterpret_cast<const short8v*>(&lds[bidx]);
            acc[0][nt] = __builtin_amdgcn_mfma_f32_16x16x32_bf16(af0, bf, acc[0][nt], 0, 0, 0);
            acc[1][nt] = __builtin_amdgcn_mfma_f32_16x16x32_bf16(af1, bf, acc[1][nt], 0, 0, 0);
        }
    }

#pragma unroll
    for (int m = 0; m < 2; ++m) {
#pragma unroll
        for (int nt = 0; nt < 8; ++nt) {
            const int j = nt * 16 + r16;
            const float bv = (nt < 4 && j < N_CLASSES) ? b2[j] : 0.0f;
#pragma unroll
            for (int r = 0; r < 4; ++r) {
                const int rown = node0 + m * 16 + q * 4 + r;
                if (rown >= n) continue;
                if (nt < 4) sb2[(size_t)rown * 64 + j] = f2bf(acc[m][nt][r] + bv);
                else        z2[(size_t)rown * 64 + (j - 64)] = f2bf(acc[m][nt][r]);
            }
        }
    }
}

// ------------------------------------------- final gather: out = sb2 + mean z2
__global__ __launch_bounds__(256) void gather_out_kernel(const unsigned short* __restrict__ z2,
                                                         const unsigned short* __restrict__ sb2,
                                                         const unsigned short* __restrict__ e_src,
                                                         const int* __restrict__ row_beg,
                                                         const int* __restrict__ row_end,
                                                         const float* __restrict__ invdeg,
                                                         float* __restrict__ out, int n) {
    int t = blockIdx.x * blockDim.x + threadIdx.x;
    int node = t >> 3;
    int lane = t & 7;
    if (node >= n) return;
    int beg = row_beg[node];
    int end = row_end[node];

    float a0=0,a1=0,a2=0,a3=0,a4=0,a5=0,a6=0,a7=0;
    int i = beg;
    for (; i + 3 < end; i += 4) {
        int s0 = e_src[i], s1 = e_src[i+1], sa = e_src[i+2], sb = e_src[i+3];
        uint4 v0 = *reinterpret_cast<const uint4*>(z2 + (size_t)s0 * 64 + lane * 8);
        uint4 v1 = *reinterpret_cast<const uint4*>(z2 + (size_t)s1 * 64 + lane * 8);
        uint4 v2 = *reinterpret_cast<const uint4*>(z2 + (size_t)sa * 64 + lane * 8);
        uint4 v3 = *reinterpret_cast<const uint4*>(z2 + (size_t)sb * 64 + lane * 8);
        acc2(v0.x, a0, a1); acc2(v0.y, a2, a3); acc2(v0.z, a4, a5); acc2(v0.w, a6, a7);
        acc2(v1.x, a0, a1); acc2(v1.y, a2, a3); acc2(v1.z, a4, a5); acc2(v1.w, a6, a7);
        acc2(v2.x, a0, a1); acc2(v2.y, a2, a3); acc2(v2.z, a4, a5); acc2(v2.w, a6, a7);
        acc2(v3.x, a0, a1); acc2(v3.y, a2, a3); acc2(v3.z, a4, a5); acc2(v3.w, a6, a7);
    }
    for (; i < end; ++i) {
        int s0 = e_src[i];
        uint4 v0 = *reinterpret_cast<const uint4*>(z2 + (size_t)s0 * 64 + lane * 8);
        acc2(v0.x, a0, a1); acc2(v0.y, a2, a3); acc2(v0.z, a4, a5); acc2(v0.w, a6, a7);
    }
    const float g = invdeg[node];
    // self term (bf16)
    uint4 sv = *reinterpret_cast<const uint4*>(sb2 + (size_t)node * 64 + lane * 8);
    float s0f=0,s1f=0,s2f=0,s3f=0,s4f=0,s5f=0,s6f=0,s7f=0;
    acc2(sv.x, s0f, s1f); acc2(sv.y, s2f, s3f); acc2(sv.z, s4f, s5f); acc2(sv.w, s6f, s7f);
    float v[8] = { s0f + g*a0, s1f + g*a1, s2f + g*a2, s3f + g*a3,
                   s4f + g*a4, s5f + g*a5, s6f + g*a6, s7f + g*a7 };
    const int j0 = lane * 8;
#pragma unroll
    for (int jj = 0; jj < 8; ++jj)
        if (j0 + jj < N_CLASSES) out[(size_t)node * N_CLASSES + j0 + jj] = v[jj];
}

// ---------------------------------------------------------------- launch ---
extern "C" void kernel_launch(void* const* d_in, const int* in_sizes, int n_in,
                              void* d_out, int out_size, void* d_ws, size_t ws_size,
                              hipStream_t stream) {
    const float* x   = (const float*)d_in[0];
    const int*   src = (const int*)d_in[1];
    const int*   dst = (const int*)d_in[2];
    const float* Ws0 = (const float*)d_in[3];
    const float* Wn0 = (const float*)d_in[4];
    const float* b0  = (const float*)d_in[5];
    const float* Ws1 = (const float*)d_in[6];
    const float* Wn1 = (const float*)d_in[7];
    const float* b1  = (const float*)d_in[8];
    const float* Ws2 = (const float*)d_in[9];
    const float* Wn2 = (const float*)d_in[10];
    const float* b2  = (const float*)d_in[11];
    float* out = (float*)d_out;

    // workspace layout (~59 MB)
    char* w = (char*)d_ws;
    int*   gcursor = (int*)w;                       w += 256 * 4;
    int*   row_beg = (int*)w;                       w += NPAD * 4;
    int*   row_end = (int*)w;                       w += NPAD * 4;
    float* invdeg  = (float*)w;                     w += NPAD * 4;
    unsigned* ebuf = (unsigned*)w;                  w += (size_t)NBUK * CAP * 4;
    unsigned short* e_src = (unsigned short*)w;     w += (size_t)NBUK * CAP * 2;
    unsigned short* xb  = (unsigned short*)w;       w += (size_t)N_NODES * FEATS * 2;
    unsigned short* h1b = (unsigned short*)w;       w += (size_t)N_NODES * FEATS * 2;
    unsigned short* hnb = (unsigned short*)w;       w += (size_t)N_NODES * FEATS * 2;
    unsigned short* Wt0 = (unsigned short*)w;       w += 128 * 256 * 2;
    unsigned short* Wt1 = (unsigned short*)w;       w += 128 * 256 * 2;
    unsigned short* Wt2 = (unsigned short*)w;       w += 128 * 128 * 2;
    unsigned short* sb2 = (unsigned short*)w;       w += (size_t)N_NODES * 64 * 2;
    unsigned short* z2  = (unsigned short*)w;       w += (size_t)N_NODES * 64 * 2;  // R12: own buffer (race fix)

    const int B = 256;
    const int scat_blocks  = (N_EDGES + EB - 1) / EB;                    // 391
    const int gath_blocks  = (int)(((size_t)N_NODES * 16 + B - 1) / B);  // 3125
    const int gout_blocks  = (int)(((size_t)N_NODES * 8 + B - 1) / B);   // 1563
    const int gemm0_blocks = (N_NODES + 255) / 256;                      // 196
    const int gemm12_blocks = (N_NODES + 127) / 128;                     // 391

    // ---- prep (also zeroes gcursor; stream-ordered before scatter) ----
    prep_all<<<CVT8 + 320 + 1, B, 0, stream>>>(x, xb, Ws0, Wn0, Ws1, Wn1, Ws2, Wn2,
                                               Wt0, Wt1, Wt2, gcursor);

    // ---- CSR build: padded-bucket counting sort (structure reused x3) ----
    bucket_scatter<<<scat_blocks, B, 0, stream>>>(src, dst, gcursor, ebuf, N_EDGES);
    bucket_finalize<<<NBUK, B, 0, stream>>>(ebuf, gcursor, row_beg, row_end, invdeg, e_src);

    // ---- layer 0: xb -> h1b ----
    gather_bf16_kernel<<<gath_blocks, B, 0, stream>>>(xb, e_src, row_beg, row_end, invdeg, hnb, N_NODES);
    sage_gemm<<<gemm0_blocks, B, 0, stream>>>(xb, hnb, Wt0, b0, h1b, N_NODES);

    // ---- layer 1 + layer-2 transform (fused; h2 never leaves the block) ----
    gather_bf16_kernel<<<gath_blocks, B, 0, stream>>>(h1b, e_src, row_beg, row_end, invdeg, hnb, N_NODES);
    sage_gemm_l12<<<gemm12_blocks, B, 0, stream>>>(h1b, hnb, Wt1, b1, Wt2, b2, sb2, z2, N_NODES);

    // ---- final: out = sb2 + invdeg * sum z2[src] ----
    gather_out_kernel<<<gout_blocks, B, 0, stream>>>(z2, sb2, e_src, row_beg, row_end,
                                                     invdeg, out, N_NODES);
}

// Round 13
// 142.094 us; speedup vs baseline: 1.0189x; 1.0189x over previous
//
#include <hip/hip_runtime.h>

#define N_NODES 50000
#define N_EDGES 800000
#define FEATS   128
#define N_CLASSES 47
#define NPAD    50176        // 196 * 256
#define NBUK    196          // buckets of 256 nodes (dst >> 8)
#define EB      2048         // edges per bucket_scatter block
#define CAP     6144         // padded bucket capacity (avg 4096, sigma 64 -> +32 sigma)
#define CVT8    ((N_NODES * FEATS / 8 + 255) / 256)   // 3125 blocks for x->bf16

typedef __attribute__((ext_vector_type(8))) short short8v;   // 8 bf16 = 4 VGPRs
typedef __attribute__((ext_vector_type(4))) float float4v;   // 4 f32 acc

// ------------------------------------------------------------ bf16 helpers --
static __device__ __forceinline__ unsigned short f2bf(float f) {
    union { float f; unsigned u; } v; v.f = f;
    return (unsigned short)((v.u + 0x7fffu + ((v.u >> 16) & 1u)) >> 16);  // RNE
}
static __device__ __forceinline__ unsigned pack2(float a, float b) {
    return (unsigned)f2bf(a) | ((unsigned)f2bf(b) << 16);
}
static __device__ __forceinline__ void acc2(unsigned u, float& a, float& b) {
    union { unsigned u; float f; } lo, hi;
    lo.u = u << 16; hi.u = u & 0xffff0000u;
    a += lo.f; b += hi.f;
}

// ===================== prep: x->bf16, W->bf16^T, gcursor=0 (one kernel) =====
__global__ __launch_bounds__(256) void prep_all(const float* __restrict__ x,
                                                unsigned short* __restrict__ xb,
                                                const float* __restrict__ Ws0,
                                                const float* __restrict__ Wn0,
                                                const float* __restrict__ Ws1,
                                                const float* __restrict__ Wn1,
                                                const float* __restrict__ Ws2,
                                                const float* __restrict__ Wn2,
                                                unsigned short* __restrict__ Wt0,
                                                unsigned short* __restrict__ Wt1,
                                                unsigned short* __restrict__ Wt2,
                                                int* __restrict__ gcursor) {
    const int b = blockIdx.x;
    if (b < CVT8) {
        const int t = b * 256 + threadIdx.x;
        if (t < N_NODES * FEATS / 8) {
            const float4* p = reinterpret_cast<const float4*>(x + (size_t)t * 8);
            float4 a = p[0], c = p[1];
            uint4 o;
            o.x = pack2(a.x, a.y); o.y = pack2(a.z, a.w);
            o.z = pack2(c.x, c.y); o.w = pack2(c.z, c.w);
            *reinterpret_cast<uint4*>(xb + (size_t)t * 8) = o;
        }
    } else if (b < CVT8 + 256) {
        // Wt0 / Wt1: [j][k], k<128 -> Ws[k][j], else Wn[k-128][j]
        const int t = (b - CVT8) * 256 + threadIdx.x;    // < 256*256
        const int j = t >> 8, k = t & 255;
        const float* Ws; const float* Wn; unsigned short* Wt; size_t idx; int jj;
        if (j < 128) { Ws = Ws0; Wn = Wn0; Wt = Wt0; idx = (size_t)j * 256 + k; jj = j; }
        else         { Ws = Ws1; Wn = Wn1; Wt = Wt1; idx = (size_t)(j - 128) * 256 + k; jj = j - 128; }
        const float v = (k < 128) ? Ws[(size_t)k * 128 + jj] : Wn[(size_t)(k - 128) * 128 + jj];
        Wt[idx] = f2bf(v);
    } else if (b < CVT8 + 320) {
        // Wt2: [j2][k], j2<64 -> Ws2 col j2 (47 used), j2>=64 -> Wn2 col j2-64; K=128
        const int wb2 = b - CVT8 - 256;                  // 0..63
        const int j2 = wb2 * 2 + (threadIdx.x >> 7);     // 0..127
        const int k  = threadIdx.x & 127;
        float v = 0.0f;
        if (j2 < 64) { if (j2 < N_CLASSES) v = Ws2[(size_t)k * N_CLASSES + j2]; }
        else { const int jn = j2 - 64; if (jn < N_CLASSES) v = Wn2[(size_t)k * N_CLASSES + jn]; }
        Wt2[(size_t)j2 * 128 + k] = f2bf(v);
    } else {
        gcursor[threadIdx.x] = 0;
    }
}

// ============================ CSR build (bucket counting sort) ==============
__global__ __launch_bounds__(256) void bucket_scatter(const int* __restrict__ src,
                                                      const int* __restrict__ dst,
                                                      int* __restrict__ gcursor,
                                                      unsigned* __restrict__ ebuf, int E) {
    __shared__ int hist[NBUK], lscan[NBUK], lcur[NBUK], sbase[NBUK];
    __shared__ int s[256];
    __shared__ unsigned stage[EB];                    // 8 KB
    const int t = threadIdx.x;
    const int e0 = blockIdx.x * EB;
    const int tot = min(EB, E - e0);

    unsigned pk[8]; int bk[8];
#pragma unroll
    for (int k = 0; k < 8; ++k) {
        const int i = k * 256 + t;
        if (i < tot) {
            const int d = dst[e0 + i];
            pk[k] = ((unsigned)src[e0 + i] << 16) | (unsigned)d;
            bk[k] = d >> 8;
        } else { pk[k] = 0; bk[k] = -1; }
    }

    if (t < NBUK) { hist[t] = 0; lcur[t] = 0; }
    __syncthreads();
#pragma unroll
    for (int k = 0; k < 8; ++k)
        if (bk[k] >= 0) atomicAdd(&hist[bk[k]], 1);
    __syncthreads();

    const int v = (t < NBUK) ? hist[t] : 0;
    s[t] = v;
    __syncthreads();
    for (int off = 1; off < 256; off <<= 1) {
        int x = (t >= off) ? s[t - off] : 0;
        __syncthreads();
        s[t] += x;
        __syncthreads();
    }
    if (t < NBUK) {
        lscan[t] = s[t] - v;
        sbase[t] = v ? atomicAdd(&gcursor[t], v) : 0;
    }
    __syncthreads();

#pragma unroll
    for (int k = 0; k < 8; ++k) {
        if (bk[k] >= 0) {
            const int p = lscan[bk[k]] + atomicAdd(&lcur[bk[k]], 1);
            stage[p] = pk[k];
        }
    }
    __syncthreads();

    for (int i = t; i < tot; i += 256) {
        const unsigned p = stage[i];
        const int b = (int)((p & 0xffffu) >> 8);
        const int off = sbase[b] + (i - lscan[b]);
        if (off < CAP) ebuf[(size_t)b * CAP + off] = p;   // guard: statistically dead
    }
}

__global__ __launch_bounds__(256) void bucket_finalize(const unsigned* __restrict__ ebuf,
                                                       const int* __restrict__ gcursor,
                                                       int* __restrict__ row_beg,
                                                       int* __restrict__ row_end,
                                                       float* __restrict__ invdeg,
                                                       unsigned short* __restrict__ e_src) {
    __shared__ int hist[256], lscan[256], lcur[256], s[256];
    const int b = blockIdx.x, t = threadIdx.x;
    hist[t] = 0; lcur[t] = 0;
    __syncthreads();

    const int base = b * CAP;
    const int cnt  = min(gcursor[b], CAP);
    for (int i = t; i < cnt; i += 256)
        atomicAdd(&hist[ebuf[base + i] & 255], 1);
    __syncthreads();

    const int v = hist[t];
    s[t] = v;
    __syncthreads();
    for (int off = 1; off < 256; off <<= 1) {
        int x = (t >= off) ? s[t - off] : 0;
        __syncthreads();
        s[t] += x;
        __syncthreads();
    }
    lscan[t] = s[t] - v;
    __syncthreads();

    const int gnode = b * 256 + t;
    row_beg[gnode] = base + lscan[t];
    row_end[gnode] = base + lscan[t] + v;
    invdeg[gnode]  = 1.0f / fmaxf((float)v, 1.0f);

    for (int i = t; i < cnt; i += 256) {
        const unsigned p = ebuf[base + i];
        const int dl = p & 255;
        const int pos = base + lscan[dl] + atomicAdd(&lcur[dl], 1);
        e_src[pos] = (unsigned short)(p >> 16);
    }
}

// --------------------------------------------------------- CSR mean-gather --
// 16 lanes per node; lane handles feats [8*lane, 8*lane+8). bf16 in, f32 acc,
// bf16 out (pre-scaled by invdeg). 4-deep ILP; high occupancy (no LDS) —
// R9 lesson: this latency/L3-bound phase must NOT be fused behind big LDS.
__global__ __launch_bounds__(256) void gather_bf16_kernel(const unsigned short* __restrict__ hb,
                                                          const unsigned short* __restrict__ e_src,
                                                          const int* __restrict__ row_beg,
                                                          const int* __restrict__ row_end,
                                                          const float* __restrict__ invdeg,
                                                          unsigned short* __restrict__ hnb,
                                                          int n) {
    int t = blockIdx.x * blockDim.x + threadIdx.x;
    int node = t >> 4;
    int lane = t & 15;
    if (node >= n) return;
    int beg = row_beg[node];
    int end = row_end[node];

    float a0=0,a1=0,a2=0,a3=0,a4=0,a5=0,a6=0,a7=0;
    int i = beg;
    for (; i + 3 < end; i += 4) {
        int s0 = e_src[i], s1 = e_src[i+1], s2 = e_src[i+2], s3 = e_src[i+3];
        uint4 v0 = *reinterpret_cast<const uint4*>(hb + (size_t)s0 * FEATS + lane * 8);
        uint4 v1 = *reinterpret_cast<const uint4*>(hb + (size_t)s1 * FEATS + lane * 8);
        uint4 v2 = *reinterpret_cast<const uint4*>(hb + (size_t)s2 * FEATS + lane * 8);
        uint4 v3 = *reinterpret_cast<const uint4*>(hb + (size_t)s3 * FEATS + lane * 8);
        acc2(v0.x, a0, a1); acc2(v0.y, a2, a3); acc2(v0.z, a4, a5); acc2(v0.w, a6, a7);
        acc2(v1.x, a0, a1); acc2(v1.y, a2, a3); acc2(v1.z, a4, a5); acc2(v1.w, a6, a7);
        acc2(v2.x, a0, a1); acc2(v2.y, a2, a3); acc2(v2.z, a4, a5); acc2(v2.w, a6, a7);
        acc2(v3.x, a0, a1); acc2(v3.y, a2, a3); acc2(v3.z, a4, a5); acc2(v3.w, a6, a7);
    }
    for (; i < end; ++i) {
        int s0 = e_src[i];
        uint4 v0 = *reinterpret_cast<const uint4*>(hb + (size_t)s0 * FEATS + lane * 8);
        acc2(v0.x, a0, a1); acc2(v0.y, a2, a3); acc2(v0.z, a4, a5); acc2(v0.w, a6, a7);
    }
    const float g = invdeg[node];
    uint4 o;
    o.x = pack2(a0 * g, a1 * g); o.y = pack2(a2 * g, a3 * g);
    o.z = pack2(a4 * g, a5 * g); o.w = pack2(a6 * g, a7 * g);
    *reinterpret_cast<uint4*>(hnb + (size_t)node * FEATS + lane * 8) = o;
}

// ------------------------------------------------------- MFMA fused GEMM ----
// Layer 0: C[M,128] = [hb|hnb](bf16, K=256) @ Wt^T + bias, ReLU, bf16 out.
// 128 nodes/block (R12's 256-wide regressed: 196 blocks < 256 CUs).
// Wt staged with XOR swizzle (ushort idx ^= (row&7)<<3) -> conflict-free
// ds_read_b128. C/D: col=lane&15, row=(lane>>4)*4+reg (m89-verified).
__global__ __launch_bounds__(256) void sage_gemm(const unsigned short* __restrict__ hb,
                                                 const unsigned short* __restrict__ hnb,
                                                 const unsigned short* __restrict__ Wt,
                                                 const float* __restrict__ bias,
                                                 unsigned short* __restrict__ outb, int n) {
    __shared__ unsigned short lds[128 * 256];        // 64KB
    const int t = threadIdx.x;
#pragma unroll
    for (int it = 0; it < 16; ++it) {
        int g = (it * 256 + t) * 8;
        int row = g >> 8;
        int swz = g ^ ((row & 7) << 3);
        *reinterpret_cast<uint4*>(&lds[swz]) = *reinterpret_cast<const uint4*>(Wt + g);
    }
    __syncthreads();

    const int lane = t & 63, wave = t >> 6;
    const int node0 = blockIdx.x * 128 + wave * 32;  // wave owns rows [node0, node0+32)
    const int r16 = lane & 15, q = lane >> 4;
    const int arown0 = node0 + r16;
    const int arown1 = node0 + 16 + r16;
    const int arow0 = (arown0 < n) ? arown0 : 0;
    const int arow1 = (arown1 < n) ? arown1 : 0;

    float4v acc[2][8];
#pragma unroll
    for (int m = 0; m < 2; ++m)
#pragma unroll
        for (int nt = 0; nt < 8; ++nt) acc[m][nt] = float4v{0.f, 0.f, 0.f, 0.f};

#pragma unroll
    for (int ks = 0; ks < 8; ++ks) {                 // k = ks*32; first 4 from hb
        const unsigned short* abase = (ks < 4) ? hb : hnb;
        const int kk = (ks & 3) * 32 + q * 8;
        short8v af0 = *reinterpret_cast<const short8v*>(abase + (size_t)arow0 * FEATS + kk);
        short8v af1 = *reinterpret_cast<const short8v*>(abase + (size_t)arow1 * FEATS + kk);
#pragma unroll
        for (int nt = 0; nt < 8; ++nt) {
            const int brow = nt * 16 + r16;
            int bidx = ((brow << 8) + ks * 32 + q * 8) ^ ((brow & 7) << 3);
            short8v bf = *reinterpret_cast<const short8v*>(&lds[bidx]);
            acc[0][nt] = __builtin_amdgcn_mfma_f32_16x16x32_bf16(af0, bf, acc[0][nt], 0, 0, 0);
            acc[1][nt] = __builtin_amdgcn_mfma_f32_16x16x32_bf16(af1, bf, acc[1][nt], 0, 0, 0);
        }
    }

#pragma unroll
    for (int m = 0; m < 2; ++m) {
#pragma unroll
        for (int nt = 0; nt < 8; ++nt) {
            const int j = nt * 16 + r16;             // C col = lane&15
            const float bv = bias[j];
#pragma unroll
            for (int r = 0; r < 4; ++r) {
                const int rown = node0 + m * 16 + q * 4 + r;  // C row
                if (rown >= n) continue;
                outb[(size_t)rown * 128 + j] = f2bf(fmaxf(acc[m][nt][r] + bv, 0.0f));
            }
        }
    }
}

// ================= fused layers 1+2: GEMM1 -> LDS h2 tile -> dual GEMM2 =====
// Stage A (K=256): h2 = relu([h1|hn1] @ Wt1 + b1) for the block's 128 rows.
// h2 @ Wt2 is ROW-LOCAL, so stage B runs in the same block: after a barrier
// the Wt1 LDS is dead; overlay h2 tile (32KB, rows swizzled) + Wt2 (32KB).
// Stage B (K=128): s2 = h2 @ Ws2 + b2 (f32), z2 = h2 @ Wn2 (bf16).
// z2 is a SEPARATE buffer (R12 race fix — R11 aliased z2=hnb and block g's
// z2 writes landed in block g/2's stage-A input; passed only by timing luck).
__global__ __launch_bounds__(256) void sage_gemm_l12(const unsigned short* __restrict__ hb,
                                                     const unsigned short* __restrict__ hnb,
                                                     const unsigned short* __restrict__ Wt1,
                                                     const float* __restrict__ b1,
                                                     const unsigned short* __restrict__ Wt2,
                                                     const float* __restrict__ b2,
                                                     float* __restrict__ s2,
                                                     unsigned short* __restrict__ z2, int n) {
    __shared__ unsigned short lds[128 * 256];        // 64KB, overlaid per phase
    const int t = threadIdx.x;
#pragma unroll
    for (int it = 0; it < 16; ++it) {
        int g = (it * 256 + t) * 8;
        int row = g >> 8;
        int swz = g ^ ((row & 7) << 3);
        *reinterpret_cast<uint4*>(&lds[swz]) = *reinterpret_cast<const uint4*>(Wt1 + g);
    }
    __syncthreads();

    const int lane = t & 63, wave = t >> 6;
    const int node0 = blockIdx.x * 128 + wave * 32;
    const int lrow0 = wave * 32;                     // block-local row base of this wave
    const int r16 = lane & 15, q = lane >> 4;
    const int arown0 = node0 + r16;
    const int arown1 = node0 + 16 + r16;
    const int arow0 = (arown0 < n) ? arown0 : 0;
    const int arow1 = (arown1 < n) ? arown1 : 0;

    float4v acc[2][8];
#pragma unroll
    for (int m = 0; m < 2; ++m)
#pragma unroll
        for (int nt = 0; nt < 8; ++nt) acc[m][nt] = float4v{0.f, 0.f, 0.f, 0.f};

    // ---- stage A: K=256 over [hb|hnb] ----
#pragma unroll
    for (int ks = 0; ks < 8; ++ks) {
        const unsigned short* abase = (ks < 4) ? hb : hnb;
        const int kk = (ks & 3) * 32 + q * 8;
        short8v af0 = *reinterpret_cast<const short8v*>(abase + (size_t)arow0 * FEATS + kk);
        short8v af1 = *reinterpret_cast<const short8v*>(abase + (size_t)arow1 * FEATS + kk);
#pragma unroll
        for (int nt = 0; nt < 8; ++nt) {
            const int brow = nt * 16 + r16;
            int bidx = ((brow << 8) + ks * 32 + q * 8) ^ ((brow & 7) << 3);
            short8v bf = *reinterpret_cast<const short8v*>(&lds[bidx]);
            acc[0][nt] = __builtin_amdgcn_mfma_f32_16x16x32_bf16(af0, bf, acc[0][nt], 0, 0, 0);
            acc[1][nt] = __builtin_amdgcn_mfma_f32_16x16x32_bf16(af1, bf, acc[1][nt], 0, 0, 0);
        }
    }
    __syncthreads();                                 // all Wt1 reads done; LDS reusable

    // ---- overlay: h2 tile [128][128] bf16 at lds[0..16384) (row-swizzled) ----
    //                Wt2   [128][128] bf16 at lds[16384..32768)
#pragma unroll
    for (int m = 0; m < 2; ++m) {
#pragma unroll
        for (int nt = 0; nt < 8; ++nt) {
            const int col = nt * 16 + r16;
            const float bv = b1[col];
#pragma unroll
            for (int r = 0; r < 4; ++r) {
                const int lr = lrow0 + m * 16 + q * 4 + r;
                const int hidx = ((lr << 7) + col) ^ ((lr & 7) << 3);
                lds[hidx] = f2bf(fmaxf(acc[m][nt][r] + bv, 0.0f));
            }
        }
    }
#pragma unroll
    for (int it = 0; it < 8; ++it) {                 // stage Wt2 (32 KB)
        int g = (it * 256 + t) * 8;
        int row = g >> 7;
        int swz = g ^ ((row & 7) << 3);
        *reinterpret_cast<uint4*>(&lds[16384 + swz]) = *reinterpret_cast<const uint4*>(Wt2 + g);
    }
    __syncthreads();

    // ---- stage B: K=128 over h2 tile ----
#pragma unroll
    for (int m = 0; m < 2; ++m)
#pragma unroll
        for (int nt = 0; nt < 8; ++nt) acc[m][nt] = float4v{0.f, 0.f, 0.f, 0.f};

#pragma unroll
    for (int ks = 0; ks < 4; ++ks) {
        const int kk = ks * 32 + q * 8;
        const int ar0 = lrow0 + r16, ar1 = lrow0 + 16 + r16;
        const int aidx0 = ((ar0 << 7) + kk) ^ ((ar0 & 7) << 3);
        const int aidx1 = ((ar1 << 7) + kk) ^ ((ar1 & 7) << 3);
        short8v af0 = *reinterpret_cast<const short8v*>(&lds[aidx0]);
        short8v af1 = *reinterpret_cast<const short8v*>(&lds[aidx1]);
#pragma unroll
        for (int nt = 0; nt < 8; ++nt) {
            const int brow = nt * 16 + r16;
            int bidx = 16384 + (((brow << 7) + kk) ^ ((brow & 7) << 3));
            short8v bf = *reinterpret_cast<const short8v*>(&lds[bidx]);
            acc[0][nt] = __builtin_amdgcn_mfma_f32_16x16x32_bf16(af0, bf, acc[0][nt], 0, 0, 0);
            acc[1][nt] = __builtin_amdgcn_mfma_f32_16x16x32_bf16(af1, bf, acc[1][nt], 0, 0, 0);
        }
    }

#pragma unroll
    for (int m = 0; m < 2; ++m) {
#pragma unroll
        for (int nt = 0; nt < 8; ++nt) {
            const int j = nt * 16 + r16;
            const float bv = (nt < 4 && j < N_CLASSES) ? b2[j] : 0.0f;
#pragma unroll
            for (int r = 0; r < 4; ++r) {
                const int rown = node0 + m * 16 + q * 4 + r;
                if (rown >= n) continue;
                if (nt < 4) s2[(size_t)rown * 64 + j] = acc[m][nt][r] + bv;
                else        z2[(size_t)rown * 64 + (j - 64)] = f2bf(acc[m][nt][r]);
            }
        }
    }
}

// ------------------------------------------- final gather: out = s2 + mean z2
__global__ __launch_bounds__(256) void gather_out_kernel(const unsigned short* __restrict__ z2,
                                                         const float* __restrict__ s2,
                                                         const unsigned short* __restrict__ e_src,
                                                         const int* __restrict__ row_beg,
                                                         const int* __restrict__ row_end,
                                                         const float* __restrict__ invdeg,
                                                         float* __restrict__ out, int n) {
    int t = blockIdx.x * blockDim.x + threadIdx.x;
    int node = t >> 3;
    int lane = t & 7;
    if (node >= n) return;
    int beg = row_beg[node];
    int end = row_end[node];

    float a0=0,a1=0,a2=0,a3=0,a4=0,a5=0,a6=0,a7=0;
    int i = beg;
    for (; i + 3 < end; i += 4) {
        int s0 = e_src[i], s1 = e_src[i+1], sa = e_src[i+2], sb = e_src[i+3];
        uint4 v0 = *reinterpret_cast<const uint4*>(z2 + (size_t)s0 * 64 + lane * 8);
        uint4 v1 = *reinterpret_cast<const uint4*>(z2 + (size_t)s1 * 64 + lane * 8);
        uint4 v2 = *reinterpret_cast<const uint4*>(z2 + (size_t)sa * 64 + lane * 8);
        uint4 v3 = *reinterpret_cast<const uint4*>(z2 + (size_t)sb * 64 + lane * 8);
        acc2(v0.x, a0, a1); acc2(v0.y, a2, a3); acc2(v0.z, a4, a5); acc2(v0.w, a6, a7);
        acc2(v1.x, a0, a1); acc2(v1.y, a2, a3); acc2(v1.z, a4, a5); acc2(v1.w, a6, a7);
        acc2(v2.x, a0, a1); acc2(v2.y, a2, a3); acc2(v2.z, a4, a5); acc2(v2.w, a6, a7);
        acc2(v3.x, a0, a1); acc2(v3.y, a2, a3); acc2(v3.z, a4, a5); acc2(v3.w, a6, a7);
    }
    for (; i < end; ++i) {
        int s0 = e_src[i];
        uint4 v0 = *reinterpret_cast<const uint4*>(z2 + (size_t)s0 * 64 + lane * 8);
        acc2(v0.x, a0, a1); acc2(v0.y, a2, a3); acc2(v0.z, a4, a5); acc2(v0.w, a6, a7);
    }
    const float g = invdeg[node];
    const float4 sa4 = *reinterpret_cast<const float4*>(s2 + (size_t)node * 64 + lane * 8);
    const float4 sb4 = *reinterpret_cast<const float4*>(s2 + (size_t)node * 64 + lane * 8 + 4);
    float v[8] = { sa4.x + g*a0, sa4.y + g*a1, sa4.z + g*a2, sa4.w + g*a3,
                   sb4.x + g*a4, sb4.y + g*a5, sb4.z + g*a6, sb4.w + g*a7 };
    const int j0 = lane * 8;
#pragma unroll
    for (int jj = 0; jj < 8; ++jj)
        if (j0 + jj < N_CLASSES) out[(size_t)node * N_CLASSES + j0 + jj] = v[jj];
}

// ---------------------------------------------------------------- launch ---
extern "C" void kernel_launch(void* const* d_in, const int* in_sizes, int n_in,
                              void* d_out, int out_size, void* d_ws, size_t ws_size,
                              hipStream_t stream) {
    const float* x   = (const float*)d_in[0];
    const int*   src = (const int*)d_in[1];
    const int*   dst = (const int*)d_in[2];
    const float* Ws0 = (const float*)d_in[3];
    const float* Wn0 = (const float*)d_in[4];
    const float* b0  = (const float*)d_in[5];
    const float* Ws1 = (const float*)d_in[6];
    const float* Wn1 = (const float*)d_in[7];
    const float* b1  = (const float*)d_in[8];
    const float* Ws2 = (const float*)d_in[9];
    const float* Wn2 = (const float*)d_in[10];
    const float* b2  = (const float*)d_in[11];
    float* out = (float*)d_out;

    // workspace layout (~66 MB)
    char* w = (char*)d_ws;
    int*   gcursor = (int*)w;                       w += 256 * 4;
    int*   row_beg = (int*)w;                       w += NPAD * 4;
    int*   row_end = (int*)w;                       w += NPAD * 4;
    float* invdeg  = (float*)w;                     w += NPAD * 4;
    unsigned* ebuf = (unsigned*)w;                  w += (size_t)NBUK * CAP * 4;
    unsigned short* e_src = (unsigned short*)w;     w += (size_t)NBUK * CAP * 2;
    unsigned short* xb  = (unsigned short*)w;       w += (size_t)N_NODES * FEATS * 2;
    unsigned short* h1b = (unsigned short*)w;       w += (size_t)N_NODES * FEATS * 2;
    unsigned short* hnb = (unsigned short*)w;       w += (size_t)N_NODES * FEATS * 2;
    unsigned short* Wt0 = (unsigned short*)w;       w += 128 * 256 * 2;
    unsigned short* Wt1 = (unsigned short*)w;       w += 128 * 256 * 2;
    unsigned short* Wt2 = (unsigned short*)w;       w += 128 * 128 * 2;
    float* s2 = (float*)w;                          w += (size_t)N_NODES * 64 * 4;
    unsigned short* z2 = (unsigned short*)w;        w += (size_t)N_NODES * 64 * 2;  // own buffer (race fix)

    const int B = 256;
    const int scat_blocks  = (N_EDGES + EB - 1) / EB;                    // 391
    const int gath_blocks  = (int)(((size_t)N_NODES * 16 + B - 1) / B);  // 3125
    const int gout_blocks  = (int)(((size_t)N_NODES * 8 + B - 1) / B);   // 1563
    const int gemm_blocks  = (N_NODES + 127) / 128;                      // 391

    // ---- prep (also zeroes gcursor; stream-ordered before scatter) ----
    prep_all<<<CVT8 + 320 + 1, B, 0, stream>>>(x, xb, Ws0, Wn0, Ws1, Wn1, Ws2, Wn2,
                                               Wt0, Wt1, Wt2, gcursor);

    // ---- CSR build: padded-bucket counting sort (structure reused x3) ----
    bucket_scatter<<<scat_blocks, B, 0, stream>>>(src, dst, gcursor, ebuf, N_EDGES);
    bucket_finalize<<<NBUK, B, 0, stream>>>(ebuf, gcursor, row_beg, row_end, invdeg, e_src);

    // ---- layer 0: xb -> h1b ----
    gather_bf16_kernel<<<gath_blocks, B, 0, stream>>>(xb, e_src, row_beg, row_end, invdeg, hnb, N_NODES);
    sage_gemm<<<gemm_blocks, B, 0, stream>>>(xb, hnb, Wt0, b0, h1b, N_NODES);

    // ---- layer 1 + layer-2 transform (fused; h2 never leaves the block) ----
    gather_bf16_kernel<<<gath_blocks, B, 0, stream>>>(h1b, e_src, row_beg, row_end, invdeg, hnb, N_NODES);
    sage_gemm_l12<<<gemm_blocks, B, 0, stream>>>(h1b, hnb, Wt1, b1, Wt2, b2, s2, z2, N_NODES);

    // ---- final: out = s2 + invdeg * sum z2[src] ----
    gather_out_kernel<<<gout_blocks, B, 0, stream>>>(z2, s2, e_src, row_beg, row_end,
                                                     invdeg, out, N_NODES);
}